// Round 1
// baseline (571.670 us; speedup 1.0000x reference)
//
#include <hip/hip_runtime.h>

// DCNv4: x(8,64,64,256) -> dwconv3x3 -> om GEMM(256->864) -> deformable
// bilinear sampling (G=32, GC=8, 9 taps) weighted by mask -> out GEMM(256->256)
// All fp32. Round 0: correctness-first fused structure.

namespace {
constexpr int NN = 8, HH = 64, WW = 64, CC = 256;
constexpr int G = 32, GC = 8, KK = 9, OMD = 864;  // OMD = G*KK*3
constexpr int NPIX = NN * HH * WW;                 // 32768
}

// ---------------- generic 256->256 GEMM: out[p][c] = sum_k in[p][k]*w[k][c] (+bias)
// One block = PT pixels, 256 threads (one output column each).
// Safe for in==out: all global reads of `in` complete before any write.
template <int PT, bool HAS_BIAS>
__global__ __launch_bounds__(256) void gemm256_kernel(
    const float* __restrict__ in, const float* __restrict__ w,
    const float* __restrict__ bias, float* __restrict__ out) {
  __shared__ float xs[PT][CC];
  const int t = threadIdx.x;
  const int pix0 = blockIdx.x * PT;
  for (int p = 0; p < PT; ++p) xs[p][t] = in[(size_t)(pix0 + p) * CC + t];
  __syncthreads();

  float acc[PT];
  const float b = HAS_BIAS ? bias[t] : 0.0f;
#pragma unroll
  for (int p = 0; p < PT; ++p) acc[p] = b;

  for (int k = 0; k < CC; k += 4) {
    const float w0 = w[(size_t)(k + 0) * CC + t];
    const float w1 = w[(size_t)(k + 1) * CC + t];
    const float w2 = w[(size_t)(k + 2) * CC + t];
    const float w3 = w[(size_t)(k + 3) * CC + t];
#pragma unroll
    for (int p = 0; p < PT; ++p) {
      const float4 xv = *(const float4*)&xs[p][k];
      acc[p] = fmaf(xv.x, w0, acc[p]);
      acc[p] = fmaf(xv.y, w1, acc[p]);
      acc[p] = fmaf(xv.z, w2, acc[p]);
      acc[p] = fmaf(xv.w, w3, acc[p]);
    }
  }
  for (int p = 0; p < PT; ++p) out[(size_t)(pix0 + p) * CC + t] = acc[p];
}

// ---------------- fused: dwconv3x3 -> om GEMM (256->864) -> deformable sampling
// One block = PT pixels (PT=8, one row segment), 256 threads.
template <int PT>
__global__ __launch_bounds__(256) void om_sample_kernel(
    const float* __restrict__ x, const float* __restrict__ dw_w,
    const float* __restrict__ dw_b, const float* __restrict__ om_w,
    const float* __restrict__ om_b, const float* __restrict__ value,
    float* __restrict__ sampled) {
  __shared__ float xs[PT][CC];     // depthwise-conv rows (K-vector for om GEMM)
  __shared__ float s_om[PT][OMD];  // om rows: per pixel 32 groups x 27
  const int t = threadIdx.x;
  const int pix0 = blockIdx.x * PT;

  // ---- Stage A: depthwise 3x3 conv (SAME, zero pad), channel t for PT pixels
  {
    const float b = dw_b[t];
    float dw[9];
#pragma unroll
    for (int i = 0; i < 9; ++i) dw[i] = dw_w[(size_t)i * CC + t];
    for (int p = 0; p < PT; ++p) {
      const int pix = pix0 + p;
      const int xw = pix & 63;
      const int y = (pix >> 6) & 63;
      const int n = pix >> 12;
      float a = b;
#pragma unroll
      for (int ky = 0; ky < 3; ++ky) {
        const int yy = y + ky - 1;
        if (yy < 0 || yy >= HH) continue;
#pragma unroll
        for (int kx = 0; kx < 3; ++kx) {
          const int xx = xw + kx - 1;
          if (xx < 0 || xx >= WW) continue;
          a = fmaf(x[(((size_t)(n * HH + yy)) * WW + xx) * CC + t], dw[ky * 3 + kx], a);
        }
      }
      xs[p][t] = a;
    }
  }
  __syncthreads();

  // ---- Stage B: om = xdw @ om_w + om_b   (864 columns; thread t does
  // columns t, t+256, t+512, and t+768 when t<96)
  {
    const int j3 = t + 768;
    const bool has4 = (j3 < OMD);
    float acc0[PT], acc1[PT], acc2[PT], acc3[PT];
    {
      const float b0 = om_b[t], b1 = om_b[t + 256], b2 = om_b[t + 512];
      const float b3 = has4 ? om_b[j3] : 0.0f;
#pragma unroll
      for (int p = 0; p < PT; ++p) {
        acc0[p] = b0; acc1[p] = b1; acc2[p] = b2; acc3[p] = b3;
      }
    }
    for (int k = 0; k < CC; k += 4) {
      float4 xv[PT];
#pragma unroll
      for (int p = 0; p < PT; ++p) xv[p] = *(const float4*)&xs[p][k];
      const float* wr = om_w + (size_t)k * OMD;
#pragma unroll
      for (int kk = 0; kk < 4; ++kk) {
        const float w0 = wr[kk * OMD + t];
        const float w1 = wr[kk * OMD + t + 256];
        const float w2 = wr[kk * OMD + t + 512];
        const float w3 = has4 ? wr[kk * OMD + j3] : 0.0f;
#pragma unroll
        for (int p = 0; p < PT; ++p) {
          const float xk = ((const float*)&xv[p])[kk];
          acc0[p] = fmaf(xk, w0, acc0[p]);
          acc1[p] = fmaf(xk, w1, acc1[p]);
          acc2[p] = fmaf(xk, w2, acc2[p]);
          acc3[p] = fmaf(xk, w3, acc3[p]);
        }
      }
    }
#pragma unroll
    for (int p = 0; p < PT; ++p) {
      s_om[p][t] = acc0[p];
      s_om[p][t + 256] = acc1[p];
      s_om[p][t + 512] = acc2[p];
      if (has4) s_om[p][j3] = acc3[p];
    }
  }
  __syncthreads();

  // ---- Stage C: deformable bilinear sampling. thread t -> (pixel p, group g)
  {
    const int p = t >> 5;         // PT=8 pixels
    const int g = t & 31;         // 32 groups
    const int pix = pix0 + p;
    const int xw = pix & 63;
    const int y = (pix >> 6) & 63;
    const int n = pix >> 12;
    const float* omr = &s_om[p][g * 27];
    const float* vbase = value + ((size_t)n * HH * WW) * CC + g * GC;

    float acc[GC];
#pragma unroll
    for (int c = 0; c < GC; ++c) acc[c] = 0.0f;

    auto corner = [&](int yy, int xx, float wt) {
      if (yy >= 0 && yy < HH && xx >= 0 && xx < WW) {
        const float* v = vbase + ((size_t)(yy * WW + xx)) * CC;
        const float4 a = *(const float4*)v;
        const float4 bb = *(const float4*)(v + 4);
        acc[0] = fmaf(wt, a.x, acc[0]);
        acc[1] = fmaf(wt, a.y, acc[1]);
        acc[2] = fmaf(wt, a.z, acc[2]);
        acc[3] = fmaf(wt, a.w, acc[3]);
        acc[4] = fmaf(wt, bb.x, acc[4]);
        acc[5] = fmaf(wt, bb.y, acc[5]);
        acc[6] = fmaf(wt, bb.z, acc[6]);
        acc[7] = fmaf(wt, bb.w, acc[7]);
      }
    };

#pragma unroll
    for (int k = 0; k < KK; ++k) {
      const float px = (float)(xw + (k % 3) - 1) + omr[2 * k];
      const float py = (float)(y + (k / 3) - 1) + omr[2 * k + 1];
      const float m = omr[18 + k];
      const float x0f = floorf(px), y0f = floorf(py);
      const float tx = px - x0f, ty = py - y0f;
      const int ix = (int)x0f, iy = (int)y0f;
      const float w00 = m * (1.0f - ty) * (1.0f - tx);
      const float w01 = m * (1.0f - ty) * tx;
      const float w10 = m * ty * (1.0f - tx);
      const float w11 = m * ty * tx;
      corner(iy, ix, w00);
      corner(iy, ix + 1, w01);
      corner(iy + 1, ix, w10);
      corner(iy + 1, ix + 1, w11);
    }

    float* orow = sampled + (size_t)pix * CC + g * GC;
    *(float4*)&orow[0] = make_float4(acc[0], acc[1], acc[2], acc[3]);
    *(float4*)&orow[4] = make_float4(acc[4], acc[5], acc[6], acc[7]);
  }
}

extern "C" void kernel_launch(void* const* d_in, const int* in_sizes, int n_in,
                              void* d_out, int out_size, void* d_ws, size_t ws_size,
                              hipStream_t stream) {
  const float* x = (const float*)d_in[0];
  const float* dw_w = (const float*)d_in[1];
  const float* dw_b = (const float*)d_in[2];
  const float* om_w = (const float*)d_in[3];
  const float* om_b = (const float*)d_in[4];
  const float* vp_w = (const float*)d_in[5];
  const float* vp_b = (const float*)d_in[6];
  const float* op_w = (const float*)d_in[7];
  float* out = (float*)d_out;
  float* value = (float*)d_ws;  // NPIX*CC floats = 32 MiB scratch

  // 1) value = x @ vp_w + vp_b
  constexpr int PT_G = 16;
  gemm256_kernel<PT_G, true><<<NPIX / PT_G, 256, 0, stream>>>(x, vp_w, vp_b, value);

  // 2) fused dwconv + om GEMM + deformable sampling -> writes `sampled` into d_out
  constexpr int PT2 = 8;
  om_sample_kernel<PT2><<<NPIX / PT2, 256, 0, stream>>>(x, dw_w, dw_b, om_w, om_b,
                                                        value, out);

  // 3) out = sampled @ op_w  (in-place: rows staged in LDS before overwrite)
  gemm256_kernel<PT_G, false><<<NPIX / PT_G, 256, 0, stream>>>(out, op_w, nullptr, out);
}

// Round 2
// 392.164 us; speedup vs baseline: 1.4577x; 1.4577x over previous
//
#include <hip/hip_runtime.h>

// DCNv4 on gfx950 — bf16 MFMA pipeline.
// K0: weights -> bf16 transposed [n][k]
// K2: dwconv3x3 (fp32 in) -> xdw bf16, also x -> x_bf16
// K1: value = x @ vp_w + vp_b      (MFMA, fp32 out)
// K3: om = xdw @ om_w + om_b (MFMA) -> LDS bf16 -> deformable sampling -> sampled bf16
// K4: out = sampled @ op_w         (MFMA, fp32 out)

typedef __bf16 bf16_t;
typedef bf16_t bf16x8 __attribute__((ext_vector_type(8)));
typedef float f32x4 __attribute__((ext_vector_type(4)));

namespace {
constexpr int NN = 8, HH = 64, WW = 64, CC = 256;
constexpr int G = 32, GC = 8, OMD = 864;      // G*9*3
constexpr int NPIX = NN * HH * WW;            // 32768
constexpr int OMD_PAD = 896;                  // 56 tiles of 16 (2 dummy)
}

// ---------------- K0: convert + transpose weights to bf16 [n][k] ----------------
// block b in [0,896): om_wT row b ; [896,1152): vp_wT ; [1152,1408): op_wT
__global__ __launch_bounds__(256) void convert_weights_kernel(
    const float* __restrict__ om_w, const float* __restrict__ vp_w,
    const float* __restrict__ op_w, bf16_t* __restrict__ om_wT,
    bf16_t* __restrict__ vp_wT, bf16_t* __restrict__ op_wT) {
  const int t = threadIdx.x;
  const int b = blockIdx.x;
  if (b < OMD_PAD) {
    om_wT[(size_t)b * CC + t] = (b < OMD) ? (bf16_t)om_w[(size_t)t * OMD + b] : (bf16_t)0.0f;
  } else if (b < OMD_PAD + 256) {
    const int n = b - OMD_PAD;
    vp_wT[(size_t)n * CC + t] = (bf16_t)vp_w[(size_t)t * CC + n];
  } else {
    const int n = b - OMD_PAD - 256;
    op_wT[(size_t)n * CC + t] = (bf16_t)op_w[(size_t)t * CC + n];
  }
}

// ---------------- K2: depthwise 3x3 conv -> bf16; also x -> bf16 ----------------
__global__ __launch_bounds__(256) void dwconv_kernel(
    const float* __restrict__ x, const float* __restrict__ dw_w,
    const float* __restrict__ dw_b, bf16_t* __restrict__ xdw,
    bf16_t* __restrict__ x_bf16) {
  const int t = threadIdx.x;
  const int pix0 = blockIdx.x * 16;
  const float bias = dw_b[t];
  float dw[9];
#pragma unroll
  for (int i = 0; i < 9; ++i) dw[i] = dw_w[(size_t)i * CC + t];
  for (int p = 0; p < 16; ++p) {
    const int pix = pix0 + p;
    const int xw = pix & 63;
    const int y = (pix >> 6) & 63;
    const int n = pix >> 12;
    float a = bias;
    float center = 0.0f;
#pragma unroll
    for (int ky = 0; ky < 3; ++ky) {
      const int yy = y + ky - 1;
      if (yy < 0 || yy >= HH) continue;
#pragma unroll
      for (int kx = 0; kx < 3; ++kx) {
        const int xx = xw + kx - 1;
        if (xx < 0 || xx >= WW) continue;
        const float v = x[(((size_t)(n * HH + yy)) * WW + xx) * CC + t];
        if (ky == 1 && kx == 1) center = v;
        a = fmaf(v, dw[ky * 3 + kx], a);
      }
    }
    xdw[(size_t)pix * CC + t] = (bf16_t)a;
    x_bf16[(size_t)pix * CC + t] = (bf16_t)center;
  }
}

// ---------------- K1/K4: 256->256 GEMM via MFMA 16x16x32 bf16 ----------------
// 16 pixels/block, 4 waves, each wave owns 4 N-tiles (64 cols).
// A: [NPIX][256] bf16 (k-contig). BT: [256][256] bf16 = W^T (k-contig per n).
template <bool HAS_BIAS>
__global__ __launch_bounds__(256) void mfma_gemm256_kernel(
    const bf16_t* __restrict__ A, const bf16_t* __restrict__ BT,
    const float* __restrict__ bias, float* __restrict__ out) {
  const int lane = threadIdx.x & 63;
  const int wave = threadIdx.x >> 6;
  const int pix0 = blockIdx.x * 16;
  const int m = lane & 15;
  const int kq = lane >> 4;

  const bf16_t* Ap = A + (size_t)(pix0 + m) * CC + kq * 8;
  const bf16_t* Bp = BT + (size_t)(wave * 64 + m) * CC + kq * 8;

  f32x4 acc[4] = {};
#pragma unroll
  for (int ks = 0; ks < 8; ++ks) {
    const bf16x8 a = *(const bf16x8*)(Ap + ks * 32);
#pragma unroll
    for (int i = 0; i < 4; ++i) {
      const bf16x8 b = *(const bf16x8*)(Bp + (size_t)i * 16 * CC + ks * 32);
      acc[i] = __builtin_amdgcn_mfma_f32_16x16x32_bf16(a, b, acc[i], 0, 0, 0);
    }
  }

  const int row0 = pix0 + kq * 4;
#pragma unroll
  for (int i = 0; i < 4; ++i) {
    const int n = wave * 64 + i * 16 + m;
    const float bs = HAS_BIAS ? bias[n] : 0.0f;
#pragma unroll
    for (int r = 0; r < 4; ++r)
      out[(size_t)(row0 + r) * CC + n] = acc[i][r] + bs;
  }
}

// ---------------- K3: om GEMM (MFMA) + deformable sampling ----------------
// 16 pixels/block, 4 waves x 14 N-tiles (56 tiles; 54 real + 2 dummy on pad).
__global__ __launch_bounds__(256) void om_sample_mfma_kernel(
    const bf16_t* __restrict__ xdw, const bf16_t* __restrict__ om_wT,
    const float* __restrict__ om_b, const float* __restrict__ value,
    bf16_t* __restrict__ sampled) {
  constexpr int SOM_LD = 868;  // padded leading dim (elements)
  __shared__ bf16_t s_om[16][SOM_LD];

  const int lane = threadIdx.x & 63;
  const int wave = threadIdx.x >> 6;
  const int pix0 = blockIdx.x * 16;
  const int m = lane & 15;
  const int kq = lane >> 4;

  // ---- MFMA phase: om[16][864] = xdw_tile @ om_w
  {
    const bf16_t* Ap = xdw + (size_t)(pix0 + m) * CC + kq * 8;
    const bf16_t* Bp = om_wT + (size_t)(wave * 14 * 16 + m) * CC + kq * 8;
    f32x4 acc[14] = {};
#pragma unroll
    for (int ks = 0; ks < 8; ++ks) {
      const bf16x8 a = *(const bf16x8*)(Ap + ks * 32);
#pragma unroll
      for (int i = 0; i < 14; ++i) {
        const bf16x8 b = *(const bf16x8*)(Bp + (size_t)i * 16 * CC + ks * 32);
        acc[i] = __builtin_amdgcn_mfma_f32_16x16x32_bf16(a, b, acc[i], 0, 0, 0);
      }
    }
#pragma unroll
    for (int i = 0; i < 14; ++i) {
      const int nt = wave * 14 + i;
      if (nt < 54) {
        const int n = nt * 16 + m;
        const float bs = om_b[n];
#pragma unroll
        for (int r = 0; r < 4; ++r)
          s_om[kq * 4 + r][n] = (bf16_t)(acc[i][r] + bs);
      }
    }
  }
  __syncthreads();

  // ---- sampling phase: 16 pixels x 32 groups = 512 tasks, 2 per thread
  for (int task = threadIdx.x; task < 512; task += 256) {
    const int p = task >> 5;
    const int g = task & 31;
    const int pix = pix0 + p;
    const int xw = pix & 63;
    const int y = (pix >> 6) & 63;
    const int n = pix >> 12;
    const bf16_t* omr = &s_om[p][g * 27];
    const float* vbase = value + ((size_t)n * HH * WW) * CC + g * GC;

    float acc[GC];
#pragma unroll
    for (int c = 0; c < GC; ++c) acc[c] = 0.0f;

    auto corner = [&](int yy, int xx, float wt) {
      if (yy >= 0 && yy < HH && xx >= 0 && xx < WW) {
        const float* v = vbase + ((size_t)(yy * WW + xx)) * CC;
        const float4 a = *(const float4*)v;
        const float4 bb = *(const float4*)(v + 4);
        acc[0] = fmaf(wt, a.x, acc[0]);
        acc[1] = fmaf(wt, a.y, acc[1]);
        acc[2] = fmaf(wt, a.z, acc[2]);
        acc[3] = fmaf(wt, a.w, acc[3]);
        acc[4] = fmaf(wt, bb.x, acc[4]);
        acc[5] = fmaf(wt, bb.y, acc[5]);
        acc[6] = fmaf(wt, bb.z, acc[6]);
        acc[7] = fmaf(wt, bb.w, acc[7]);
      }
    };

#pragma unroll
    for (int k = 0; k < 9; ++k) {
      const float px = (float)(xw + (k % 3) - 1) + (float)omr[2 * k];
      const float py = (float)(y + (k / 3) - 1) + (float)omr[2 * k + 1];
      const float mk = (float)omr[18 + k];
      const float x0f = floorf(px), y0f = floorf(py);
      const float tx = px - x0f, ty = py - y0f;
      const int ix = (int)x0f, iy = (int)y0f;
      corner(iy, ix, mk * (1.0f - ty) * (1.0f - tx));
      corner(iy, ix + 1, mk * (1.0f - ty) * tx);
      corner(iy + 1, ix, mk * ty * (1.0f - tx));
      corner(iy + 1, ix + 1, mk * ty * tx);
    }

    bf16x8 sv;
#pragma unroll
    for (int c = 0; c < GC; ++c) sv[c] = (bf16_t)acc[c];
    *(bf16x8*)(sampled + (size_t)pix * CC + g * GC) = sv;
  }
}

extern "C" void kernel_launch(void* const* d_in, const int* in_sizes, int n_in,
                              void* d_out, int out_size, void* d_ws, size_t ws_size,
                              hipStream_t stream) {
  const float* x = (const float*)d_in[0];
  const float* dw_w = (const float*)d_in[1];
  const float* dw_b = (const float*)d_in[2];
  const float* om_w = (const float*)d_in[3];
  const float* om_b = (const float*)d_in[4];
  const float* vp_w = (const float*)d_in[5];
  const float* vp_b = (const float*)d_in[6];
  const float* op_w = (const float*)d_in[7];
  float* out = (float*)d_out;

  // workspace layout
  char* ws = (char*)d_ws;
  float* value = (float*)ws;                                   // 33,554,432 B
  bf16_t* xdw = (bf16_t*)(ws + 33554432);                      // 16,777,216 B
  bf16_t* x_bf16 = (bf16_t*)(ws + 50331648);                   // 16,777,216 B
  bf16_t* sampled = x_bf16;  // aliased: x_bf16 dead after K1 (stream-ordered)
  bf16_t* om_wT = (bf16_t*)(ws + 67108864);                    // 458,752 B
  bf16_t* vp_wT = (bf16_t*)(ws + 67567616);                    // 131,072 B
  bf16_t* op_wT = (bf16_t*)(ws + 67698688);                    // 131,072 B

  // K0: weights -> bf16 transposed
  convert_weights_kernel<<<OMD_PAD + 512, 256, 0, stream>>>(om_w, vp_w, op_w,
                                                            om_wT, vp_wT, op_wT);
  // K2: dwconv -> xdw bf16, x -> x_bf16
  dwconv_kernel<<<NPIX / 16, 256, 0, stream>>>(x, dw_w, dw_b, xdw, x_bf16);
  // K1: value = x @ vp_w + vp_b
  mfma_gemm256_kernel<true><<<NPIX / 16, 256, 0, stream>>>(x_bf16, vp_wT, vp_b, value);
  // K3: om GEMM + sampling -> sampled bf16
  om_sample_mfma_kernel<<<NPIX / 16, 256, 0, stream>>>(xdw, om_wT, om_b, value, sampled);
  // K4: out = sampled @ op_w
  mfma_gemm256_kernel<false><<<NPIX / 16, 256, 0, stream>>>(sampled, op_wT, nullptr, out);
}

// Round 3
// 343.309 us; speedup vs baseline: 1.6652x; 1.1423x over previous
//
#include <hip/hip_runtime.h>

// DCNv4 on gfx950 — bf16 MFMA pipeline, branchless bf16 sampling.
// K0: weights -> bf16 transposed [n][k]
// K2: dwconv3x3 (fp32 in) -> xdw bf16, also x -> x_bf16   (float4 vectorized)
// K1: value = x @ vp_w + vp_b      (MFMA, bf16 out)
// K3: om = xdw @ om_w + om_b (MFMA) -> LDS bf16 -> branchless bilinear sampling
// K4: out = sampled @ op_w         (MFMA, fp32 out)

typedef __bf16 bf16_t;
typedef bf16_t bf16x8 __attribute__((ext_vector_type(8)));
typedef bf16_t bf16x4 __attribute__((ext_vector_type(4)));
typedef float f32x4 __attribute__((ext_vector_type(4)));

namespace {
constexpr int NN = 8, HH = 64, WW = 64, CC = 256;
constexpr int G = 32, GC = 8, OMD = 864;      // G*9*3
constexpr int NPIX = NN * HH * WW;            // 32768
constexpr int OMD_PAD = 896;                  // 56 tiles of 16 (2 dummy)
}

// ---------------- K0: convert + transpose weights to bf16 [n][k] ----------------
__global__ __launch_bounds__(256) void convert_weights_kernel(
    const float* __restrict__ om_w, const float* __restrict__ vp_w,
    const float* __restrict__ op_w, bf16_t* __restrict__ om_wT,
    bf16_t* __restrict__ vp_wT, bf16_t* __restrict__ op_wT) {
  const int t = threadIdx.x;
  const int b = blockIdx.x;
  if (b < OMD_PAD) {
    om_wT[(size_t)b * CC + t] = (b < OMD) ? (bf16_t)om_w[(size_t)t * OMD + b] : (bf16_t)0.0f;
  } else if (b < OMD_PAD + 256) {
    const int n = b - OMD_PAD;
    vp_wT[(size_t)n * CC + t] = (bf16_t)vp_w[(size_t)t * CC + n];
  } else {
    const int n = b - OMD_PAD - 256;
    op_wT[(size_t)n * CC + t] = (bf16_t)op_w[(size_t)t * CC + n];
  }
}

// ---------------- K2: depthwise 3x3 conv -> bf16; also x -> bf16 ----------------
// thread = (channel quad, pixel slot); all lanes of a wave share the pixel ->
// wave-uniform boundary branches; 16B/lane float4 loads.
__global__ __launch_bounds__(256) void dwconv_kernel(
    const float* __restrict__ x, const float* __restrict__ dw_w,
    const float* __restrict__ dw_b, bf16_t* __restrict__ xdw,
    bf16_t* __restrict__ x_bf16) {
  const int t = threadIdx.x;
  const int cq = (t & 63) * 4;  // channel base (0..252)
  const int ps = t >> 6;        // pixel slot 0..3
  const int pix0 = blockIdx.x * 16;

  const float4 bias = *(const float4*)&dw_b[cq];
  float4 dw[9];
#pragma unroll
  for (int i = 0; i < 9; ++i) dw[i] = *(const float4*)&dw_w[(size_t)i * CC + cq];

  for (int pp = 0; pp < 4; ++pp) {
    const int pix = pix0 + ps * 4 + pp;
    const int xw = pix & 63;
    const int y = (pix >> 6) & 63;
    const int n = pix >> 12;
    float4 a = bias;
    float4 center = make_float4(0.f, 0.f, 0.f, 0.f);
#pragma unroll
    for (int ky = 0; ky < 3; ++ky) {
      const int yy = y + ky - 1;
      if (yy < 0 || yy >= HH) continue;
#pragma unroll
      for (int kx = 0; kx < 3; ++kx) {
        const int xx = xw + kx - 1;
        if (xx < 0 || xx >= WW) continue;
        const float4 v = *(const float4*)&x[(((size_t)(n * HH + yy)) * WW + xx) * CC + cq];
        const float4 w = dw[ky * 3 + kx];
        a.x = fmaf(v.x, w.x, a.x);
        a.y = fmaf(v.y, w.y, a.y);
        a.z = fmaf(v.z, w.z, a.z);
        a.w = fmaf(v.w, w.w, a.w);
        if (ky == 1 && kx == 1) center = v;
      }
    }
    bf16x4 av, cv;
    av[0] = (bf16_t)a.x; av[1] = (bf16_t)a.y; av[2] = (bf16_t)a.z; av[3] = (bf16_t)a.w;
    cv[0] = (bf16_t)center.x; cv[1] = (bf16_t)center.y;
    cv[2] = (bf16_t)center.z; cv[3] = (bf16_t)center.w;
    *(bf16x4*)&xdw[(size_t)pix * CC + cq] = av;
    *(bf16x4*)&x_bf16[(size_t)pix * CC + cq] = cv;
  }
}

// ---------------- K1/K4: 256->256 GEMM via MFMA 16x16x32 bf16 ----------------
template <bool HAS_BIAS, typename OutT>
__global__ __launch_bounds__(256) void mfma_gemm256_kernel(
    const bf16_t* __restrict__ A, const bf16_t* __restrict__ BT,
    const float* __restrict__ bias, OutT* __restrict__ out) {
  const int lane = threadIdx.x & 63;
  const int wave = threadIdx.x >> 6;
  const int pix0 = blockIdx.x * 16;
  const int m = lane & 15;
  const int kq = lane >> 4;

  const bf16_t* Ap = A + (size_t)(pix0 + m) * CC + kq * 8;
  const bf16_t* Bp = BT + (size_t)(wave * 64 + m) * CC + kq * 8;

  f32x4 acc[4] = {};
#pragma unroll
  for (int ks = 0; ks < 8; ++ks) {
    const bf16x8 a = *(const bf16x8*)(Ap + ks * 32);
#pragma unroll
    for (int i = 0; i < 4; ++i) {
      const bf16x8 b = *(const bf16x8*)(Bp + (size_t)i * 16 * CC + ks * 32);
      acc[i] = __builtin_amdgcn_mfma_f32_16x16x32_bf16(a, b, acc[i], 0, 0, 0);
    }
  }

  const int row0 = pix0 + kq * 4;
#pragma unroll
  for (int i = 0; i < 4; ++i) {
    const int n = wave * 64 + i * 16 + m;
    const float bs = HAS_BIAS ? bias[n] : 0.0f;
#pragma unroll
    for (int r = 0; r < 4; ++r)
      out[(size_t)(row0 + r) * CC + n] = (OutT)(acc[i][r] + bs);
  }
}

// ---------------- K3: om GEMM (MFMA) + branchless deformable sampling ----------
__global__ __launch_bounds__(256) void om_sample_mfma_kernel(
    const bf16_t* __restrict__ xdw, const bf16_t* __restrict__ om_wT,
    const float* __restrict__ om_b, const bf16_t* __restrict__ value,
    bf16_t* __restrict__ sampled) {
  constexpr int SOM_LD = 868;  // padded leading dim (elements)
  __shared__ bf16_t s_om[16][SOM_LD];

  const int lane = threadIdx.x & 63;
  const int wave = threadIdx.x >> 6;
  const int pix0 = blockIdx.x * 16;
  const int m = lane & 15;
  const int kq = lane >> 4;

  // ---- MFMA phase: om[16][864] = xdw_tile @ om_w + b
  {
    const bf16_t* Ap = xdw + (size_t)(pix0 + m) * CC + kq * 8;
    const bf16_t* Bp = om_wT + (size_t)(wave * 14 * 16 + m) * CC + kq * 8;
    f32x4 acc[14] = {};
#pragma unroll
    for (int ks = 0; ks < 8; ++ks) {
      const bf16x8 a = *(const bf16x8*)(Ap + ks * 32);
#pragma unroll
      for (int i = 0; i < 14; ++i) {
        const bf16x8 b = *(const bf16x8*)(Bp + (size_t)i * 16 * CC + ks * 32);
        acc[i] = __builtin_amdgcn_mfma_f32_16x16x32_bf16(a, b, acc[i], 0, 0, 0);
      }
    }
#pragma unroll
    for (int i = 0; i < 14; ++i) {
      const int nt = wave * 14 + i;
      if (nt < 54) {
        const int n = nt * 16 + m;
        const float bs = om_b[n];
#pragma unroll
        for (int r = 0; r < 4; ++r)
          s_om[kq * 4 + r][n] = (bf16_t)(acc[i][r] + bs);
      }
    }
  }
  __syncthreads();

  // ---- sampling: 16 pixels x 32 groups = 512 tasks, 2/thread, branchless
  for (int task = threadIdx.x; task < 512; task += 256) {
    const int p = task >> 5;
    const int g = task & 31;
    const int pix = pix0 + p;
    const int xw = pix & 63;
    const int y = (pix >> 6) & 63;
    const int n = pix >> 12;
    const bf16_t* omr = &s_om[p][g * 27];
    const bf16_t* vbase = value + ((size_t)n * HH * WW) * CC + g * GC;

    float acc[GC];
#pragma unroll
    for (int c = 0; c < GC; ++c) acc[c] = 0.0f;

#pragma unroll
    for (int k = 0; k < 9; ++k) {
      const float px = (float)(xw + (k % 3) - 1) + (float)omr[2 * k];
      const float py = (float)(y + (k / 3) - 1) + (float)omr[2 * k + 1];
      const float mk = (float)omr[18 + k];
      const float x0f = floorf(px), y0f = floorf(py);
      const float tx = px - x0f, ty = py - y0f;
      const int ix = (int)x0f, iy = (int)y0f;

      const float vx0 = (ix >= 0 && ix < WW) ? 1.0f : 0.0f;
      const float vx1 = (ix + 1 >= 0 && ix + 1 < WW) ? 1.0f : 0.0f;
      const float vy0 = (iy >= 0 && iy < HH) ? 1.0f : 0.0f;
      const float vy1 = (iy + 1 >= 0 && iy + 1 < HH) ? 1.0f : 0.0f;
      const int ix0 = min(max(ix, 0), WW - 1);
      const int ix1 = min(max(ix + 1, 0), WW - 1);
      const int iy0 = min(max(iy, 0), HH - 1);
      const int iy1 = min(max(iy + 1, 0), HH - 1);

      const bf16x8 v00 = *(const bf16x8*)(vbase + (size_t)(iy0 * WW + ix0) * CC);
      const bf16x8 v01 = *(const bf16x8*)(vbase + (size_t)(iy0 * WW + ix1) * CC);
      const bf16x8 v10 = *(const bf16x8*)(vbase + (size_t)(iy1 * WW + ix0) * CC);
      const bf16x8 v11 = *(const bf16x8*)(vbase + (size_t)(iy1 * WW + ix1) * CC);

      const float w00 = mk * (1.0f - ty) * (1.0f - tx) * vy0 * vx0;
      const float w01 = mk * (1.0f - ty) * tx * vy0 * vx1;
      const float w10 = mk * ty * (1.0f - tx) * vy1 * vx0;
      const float w11 = mk * ty * tx * vy1 * vx1;

#pragma unroll
      for (int c = 0; c < GC; ++c) {
        float s = acc[c];
        s = fmaf(w00, (float)v00[c], s);
        s = fmaf(w01, (float)v01[c], s);
        s = fmaf(w10, (float)v10[c], s);
        s = fmaf(w11, (float)v11[c], s);
        acc[c] = s;
      }
    }

    bf16x8 sv;
#pragma unroll
    for (int c = 0; c < GC; ++c) sv[c] = (bf16_t)acc[c];
    *(bf16x8*)(sampled + (size_t)pix * CC + g * GC) = sv;
  }
}

extern "C" void kernel_launch(void* const* d_in, const int* in_sizes, int n_in,
                              void* d_out, int out_size, void* d_ws, size_t ws_size,
                              hipStream_t stream) {
  const float* x = (const float*)d_in[0];
  const float* dw_w = (const float*)d_in[1];
  const float* dw_b = (const float*)d_in[2];
  const float* om_w = (const float*)d_in[3];
  const float* om_b = (const float*)d_in[4];
  const float* vp_w = (const float*)d_in[5];
  const float* vp_b = (const float*)d_in[6];
  const float* op_w = (const float*)d_in[7];
  float* out = (float*)d_out;

  // workspace layout (bytes)
  char* ws = (char*)d_ws;
  bf16_t* value = (bf16_t*)ws;                        // 16,777,216
  bf16_t* xdw = (bf16_t*)(ws + 16777216);             // 16,777,216
  bf16_t* x_bf16 = (bf16_t*)(ws + 33554432);          // 16,777,216
  bf16_t* sampled = x_bf16;  // aliased: x_bf16 dead after K1 (stream-ordered)
  bf16_t* om_wT = (bf16_t*)(ws + 50331648);           // 458,752
  bf16_t* vp_wT = (bf16_t*)(ws + 50790400);           // 131,072
  bf16_t* op_wT = (bf16_t*)(ws + 50921472);           // 131,072

  convert_weights_kernel<<<OMD_PAD + 512, 256, 0, stream>>>(om_w, vp_w, op_w,
                                                            om_wT, vp_wT, op_wT);
  dwconv_kernel<<<NPIX / 16, 256, 0, stream>>>(x, dw_w, dw_b, xdw, x_bf16);
  mfma_gemm256_kernel<true, bf16_t><<<NPIX / 16, 256, 0, stream>>>(x_bf16, vp_wT, vp_b, value);
  om_sample_mfma_kernel<<<NPIX / 16, 256, 0, stream>>>(xdw, om_wT, om_b, value, sampled);
  mfma_gemm256_kernel<false, float><<<NPIX / 16, 256, 0, stream>>>(sampled, op_wT, nullptr, out);
}

// Round 4
// 334.781 us; speedup vs baseline: 1.7076x; 1.0255x over previous
//
#include <hip/hip_runtime.h>

// DCNv4 on gfx950 — bf16 MFMA pipeline.
// K0: weights -> bf16 transposed [n][k]
// K2: dwconv3x3 sliding-window row kernel -> xdw bf16 + x_bf16
// K1: value = x @ vp_w + vp_b      (MFMA M=32, bf16 out)
// K3: fused om GEMM (8 waves x 7 tiles) -> LDS -> 1-task/thread sampling
// K4: out = sampled @ op_w         (MFMA M=32, fp32 out)

typedef __bf16 bf16_t;
typedef bf16_t bf16x8 __attribute__((ext_vector_type(8)));
typedef bf16_t bf16x4 __attribute__((ext_vector_type(4)));
typedef float f32x4 __attribute__((ext_vector_type(4)));

namespace {
constexpr int NN = 8, HH = 64, WW = 64, CC = 256;
constexpr int G = 32, GC = 8, OMD = 864;      // G*9*3
constexpr int NPIX = NN * HH * WW;            // 32768
constexpr int OMD_PAD = 896;                  // 56 tiles of 16 (2 dummy)
}

// ---------------- K0: convert + transpose weights to bf16 [n][k] ----------------
__global__ __launch_bounds__(256) void convert_weights_kernel(
    const float* __restrict__ om_w, const float* __restrict__ vp_w,
    const float* __restrict__ op_w, bf16_t* __restrict__ om_wT,
    bf16_t* __restrict__ vp_wT, bf16_t* __restrict__ op_wT) {
  const int t = threadIdx.x;
  const int b = blockIdx.x;
  if (b < OMD_PAD) {
    om_wT[(size_t)b * CC + t] = (b < OMD) ? (bf16_t)om_w[(size_t)t * OMD + b] : (bf16_t)0.0f;
  } else if (b < OMD_PAD + 256) {
    const int n = b - OMD_PAD;
    vp_wT[(size_t)n * CC + t] = (bf16_t)vp_w[(size_t)t * CC + n];
  } else {
    const int n = b - OMD_PAD - 256;
    op_wT[(size_t)n * CC + t] = (bf16_t)op_w[(size_t)t * CC + n];
  }
}

// ---------------- K2: dwconv3x3 sliding-window; block = one image row ----------
// thread = (channel quad cq, x-segment seg). 3-column register window:
// 3 new float4 loads per output pixel instead of 9.
__global__ __launch_bounds__(256) void dwconv_row_kernel(
    const float* __restrict__ x, const float* __restrict__ dw_w,
    const float* __restrict__ dw_b, bf16_t* __restrict__ xdw,
    bf16_t* __restrict__ x_bf16) {
  const int t = threadIdx.x;
  const int cq = (t & 63) * 4;   // channel base
  const int seg = t >> 6;        // wave id = x segment (16 px each)
  const int row = blockIdx.x;    // n*64 + y
  const int y = row & 63;
  const bool up = (y > 0), dn = (y < HH - 1);
  const float* xrow = x + (size_t)row * WW * CC + cq;

  const float4 bias = *(const float4*)&dw_b[cq];
  float4 dw[9];
#pragma unroll
  for (int i = 0; i < 9; ++i) dw[i] = *(const float4*)&dw_w[(size_t)i * CC + cq];

  const float4 zero = make_float4(0.f, 0.f, 0.f, 0.f);
  auto loadcol = [&](int xx, float4 c[3]) {
    if (xx < 0 || xx >= WW) { c[0] = c[1] = c[2] = zero; return; }
    c[0] = up ? *(const float4*)(xrow + ((size_t)xx - WW) * CC) : zero;
    c[1] = *(const float4*)(xrow + (size_t)xx * CC);
    c[2] = dn ? *(const float4*)(xrow + ((size_t)xx + WW) * CC) : zero;
  };

  const int x0 = seg * 16;
  float4 cm[3], cc[3], cp[3];
  loadcol(x0 - 1, cm);
  loadcol(x0, cc);

  for (int xx = x0; xx < x0 + 16; ++xx) {
    loadcol(xx + 1, cp);
    float4 a = bias;
#pragma unroll
    for (int r = 0; r < 3; ++r) {
      const float4 w0 = dw[r * 3 + 0], w1 = dw[r * 3 + 1], w2 = dw[r * 3 + 2];
      a.x = fmaf(cm[r].x, w0.x, fmaf(cc[r].x, w1.x, fmaf(cp[r].x, w2.x, a.x)));
      a.y = fmaf(cm[r].y, w0.y, fmaf(cc[r].y, w1.y, fmaf(cp[r].y, w2.y, a.y)));
      a.z = fmaf(cm[r].z, w0.z, fmaf(cc[r].z, w1.z, fmaf(cp[r].z, w2.z, a.z)));
      a.w = fmaf(cm[r].w, w0.w, fmaf(cc[r].w, w1.w, fmaf(cp[r].w, w2.w, a.w)));
    }
    const size_t o = (size_t)(row * WW + xx) * CC + cq;
    bf16x4 av, cv;
    av[0] = (bf16_t)a.x; av[1] = (bf16_t)a.y; av[2] = (bf16_t)a.z; av[3] = (bf16_t)a.w;
    cv[0] = (bf16_t)cc[1].x; cv[1] = (bf16_t)cc[1].y;
    cv[2] = (bf16_t)cc[1].z; cv[3] = (bf16_t)cc[1].w;
    *(bf16x4*)&xdw[o] = av;
    *(bf16x4*)&x_bf16[o] = cv;
#pragma unroll
    for (int r = 0; r < 3; ++r) { cm[r] = cc[r]; cc[r] = cp[r]; }
  }
}

// ---------------- K1/K4: 256->256 GEMM, M=32/block, 8 waves ----------------
// wave: (M-half = w>>2, N-quarter = w&3).
template <bool HAS_BIAS, typename OutT>
__global__ __launch_bounds__(512) void mfma_gemm256_kernel(
    const bf16_t* __restrict__ A, const bf16_t* __restrict__ BT,
    const float* __restrict__ bias, OutT* __restrict__ out) {
  const int lane = threadIdx.x & 63;
  const int wave = threadIdx.x >> 6;
  const int pix0 = blockIdx.x * 32 + (wave >> 2) * 16;
  const int nq = wave & 3;
  const int m = lane & 15;
  const int kq = lane >> 4;

  const bf16_t* Ap = A + (size_t)(pix0 + m) * CC + kq * 8;
  const bf16_t* Bp = BT + (size_t)(nq * 64 + m) * CC + kq * 8;

  f32x4 acc[4] = {};
#pragma unroll
  for (int ks = 0; ks < 8; ++ks) {
    const bf16x8 a = *(const bf16x8*)(Ap + ks * 32);
#pragma unroll
    for (int i = 0; i < 4; ++i) {
      const bf16x8 b = *(const bf16x8*)(Bp + (size_t)i * 16 * CC + ks * 32);
      acc[i] = __builtin_amdgcn_mfma_f32_16x16x32_bf16(a, b, acc[i], 0, 0, 0);
    }
  }

  const int row0 = pix0 + kq * 4;
#pragma unroll
  for (int i = 0; i < 4; ++i) {
    const int n = nq * 64 + i * 16 + m;
    const float bs = HAS_BIAS ? bias[n] : 0.0f;
#pragma unroll
    for (int r = 0; r < 4; ++r)
      out[(size_t)(row0 + r) * CC + n] = (OutT)(acc[i][r] + bs);
  }
}

// ---------------- K3: fused om GEMM (8 waves x 7 N-tiles) + sampling ----------
__global__ __launch_bounds__(512) void om_sample_mfma_kernel(
    const bf16_t* __restrict__ xdw, const bf16_t* __restrict__ om_wT,
    const float* __restrict__ om_b, const bf16_t* __restrict__ value,
    bf16_t* __restrict__ sampled) {
  constexpr int SOM_LD = 868;
  __shared__ bf16_t s_om[16][SOM_LD];

  const int lane = threadIdx.x & 63;
  const int wave = threadIdx.x >> 6;  // 0..7
  const int pix0 = blockIdx.x * 16;
  const int m = lane & 15;
  const int kq = lane >> 4;

  // ---- MFMA phase: om[16][864] = xdw_tile @ om_w + b; wave w owns 7 N-tiles
  {
    const bf16_t* Ap = xdw + (size_t)(pix0 + m) * CC + kq * 8;
    const bf16_t* Bp = om_wT + (size_t)(wave * 7 * 16 + m) * CC + kq * 8;
    f32x4 acc[7] = {};
#pragma unroll
    for (int ks = 0; ks < 8; ++ks) {
      const bf16x8 a = *(const bf16x8*)(Ap + ks * 32);
#pragma unroll
      for (int i = 0; i < 7; ++i) {
        const bf16x8 b = *(const bf16x8*)(Bp + (size_t)i * 16 * CC + ks * 32);
        acc[i] = __builtin_amdgcn_mfma_f32_16x16x32_bf16(a, b, acc[i], 0, 0, 0);
      }
    }
#pragma unroll
    for (int i = 0; i < 7; ++i) {
      const int nt = wave * 7 + i;
      if (nt < 54) {
        const int n = nt * 16 + m;
        const float bs = om_b[n];
#pragma unroll
        for (int r = 0; r < 4; ++r)
          s_om[kq * 4 + r][n] = (bf16_t)(acc[i][r] + bs);
      }
    }
  }
  __syncthreads();

  // ---- sampling: 16 px x 32 g = 512 tasks, exactly 1 per thread, branchless
  {
    const int task = threadIdx.x;
    const int p = task >> 5;
    const int g = task & 31;
    const int pix = pix0 + p;
    const int xw = pix & 63;
    const int y = (pix >> 6) & 63;
    const int n = pix >> 12;
    const bf16_t* omr = &s_om[p][g * 27];
    const bf16_t* vbase = value + ((size_t)n * HH * WW) * CC + g * GC;

    float acc[GC];
#pragma unroll
    for (int c = 0; c < GC; ++c) acc[c] = 0.0f;

#pragma unroll
    for (int k = 0; k < 9; ++k) {
      const float px = (float)(xw + (k % 3) - 1) + (float)omr[2 * k];
      const float py = (float)(y + (k / 3) - 1) + (float)omr[2 * k + 1];
      const float mk = (float)omr[18 + k];
      const float x0f = floorf(px), y0f = floorf(py);
      const float tx = px - x0f, ty = py - y0f;
      const int ix = (int)x0f, iy = (int)y0f;

      const float vx0 = (ix >= 0 && ix < WW) ? 1.0f : 0.0f;
      const float vx1 = (ix + 1 >= 0 && ix + 1 < WW) ? 1.0f : 0.0f;
      const float vy0 = (iy >= 0 && iy < HH) ? 1.0f : 0.0f;
      const float vy1 = (iy + 1 >= 0 && iy + 1 < HH) ? 1.0f : 0.0f;
      const int ix0 = min(max(ix, 0), WW - 1);
      const int ix1 = min(max(ix + 1, 0), WW - 1);
      const int iy0 = min(max(iy, 0), HH - 1);
      const int iy1 = min(max(iy + 1, 0), HH - 1);

      const bf16x8 v00 = *(const bf16x8*)(vbase + (size_t)(iy0 * WW + ix0) * CC);
      const bf16x8 v01 = *(const bf16x8*)(vbase + (size_t)(iy0 * WW + ix1) * CC);
      const bf16x8 v10 = *(const bf16x8*)(vbase + (size_t)(iy1 * WW + ix0) * CC);
      const bf16x8 v11 = *(const bf16x8*)(vbase + (size_t)(iy1 * WW + ix1) * CC);

      const float w00 = mk * (1.0f - ty) * (1.0f - tx) * vy0 * vx0;
      const float w01 = mk * (1.0f - ty) * tx * vy0 * vx1;
      const float w10 = mk * ty * (1.0f - tx) * vy1 * vx0;
      const float w11 = mk * ty * tx * vy1 * vx1;

#pragma unroll
      for (int c = 0; c < GC; ++c) {
        float s = acc[c];
        s = fmaf(w00, (float)v00[c], s);
        s = fmaf(w01, (float)v01[c], s);
        s = fmaf(w10, (float)v10[c], s);
        s = fmaf(w11, (float)v11[c], s);
        acc[c] = s;
      }
    }

    bf16x8 sv;
#pragma unroll
    for (int c = 0; c < GC; ++c) sv[c] = (bf16_t)acc[c];
    *(bf16x8*)(sampled + (size_t)pix * CC + g * GC) = sv;
  }
}

extern "C" void kernel_launch(void* const* d_in, const int* in_sizes, int n_in,
                              void* d_out, int out_size, void* d_ws, size_t ws_size,
                              hipStream_t stream) {
  const float* x = (const float*)d_in[0];
  const float* dw_w = (const float*)d_in[1];
  const float* dw_b = (const float*)d_in[2];
  const float* om_w = (const float*)d_in[3];
  const float* om_b = (const float*)d_in[4];
  const float* vp_w = (const float*)d_in[5];
  const float* vp_b = (const float*)d_in[6];
  const float* op_w = (const float*)d_in[7];
  float* out = (float*)d_out;

  // workspace layout (bytes)
  char* ws = (char*)d_ws;
  bf16_t* value = (bf16_t*)ws;                        // 16,777,216
  bf16_t* xdw = (bf16_t*)(ws + 16777216);             // 16,777,216
  bf16_t* x_bf16 = (bf16_t*)(ws + 33554432);          // 16,777,216
  bf16_t* sampled = x_bf16;  // aliased: x_bf16 dead after K1 (stream-ordered)
  bf16_t* om_wT = (bf16_t*)(ws + 50331648);           // 458,752
  bf16_t* vp_wT = (bf16_t*)(ws + 50790400);           // 131,072
  bf16_t* op_wT = (bf16_t*)(ws + 50921472);           // 131,072

  convert_weights_kernel<<<OMD_PAD + 512, 256, 0, stream>>>(om_w, vp_w, op_w,
                                                            om_wT, vp_wT, op_wT);
  dwconv_row_kernel<<<NN * HH, 256, 0, stream>>>(x, dw_w, dw_b, xdw, x_bf16);
  mfma_gemm256_kernel<true, bf16_t><<<NPIX / 32, 512, 0, stream>>>(x_bf16, vp_wT, vp_b, value);
  om_sample_mfma_kernel<<<NPIX / 16, 512, 0, stream>>>(xdw, om_wT, om_b, value, sampled);
  mfma_gemm256_kernel<false, float><<<NPIX / 32, 512, 0, stream>>>(sampled, op_wT, nullptr, out);
}